// Round 10
// baseline (918.601 us; speedup 1.0000x reference)
//
#include <hip/hip_runtime.h>

#define NN 100000
#define NGRAPH 64
#define NPART 8
#define SRCP 8
#define SRCW 12500
#define NBKT 64  // (dstpart, src-octile) buckets
#define NPB 12500
#define DB 16
#define PW_C 2048
#define AVGLOG 3.4965075614664802f

using f32x2 = __attribute__((ext_vector_type(2))) float;
using f32x4 = __attribute__((ext_vector_type(4))) float;
using f16x2 = __attribute__((ext_vector_type(2))) _Float16;
using f16x8 = __attribute__((ext_vector_type(8))) _Float16;
using f16x4 = __attribute__((ext_vector_type(4))) _Float16;
using i32x4 = __attribute__((ext_vector_type(4))) int;

// ---------------- CSR build ----------------
// Wave-synchronous two-pass binning over 64 (dst,src-octile) buckets.
// Src-octile sub-bucketing makes colv rows src-sorted at 12500-node (1.6-2.4MB)
// granularity -> the gather's moving window fits a 4MB per-XCD L2.
__global__ __launch_bounds__(256) void k_pcnt(const int* __restrict__ ei,
                                              int* __restrict__ pcnt, int E, int W) {
  const int w = blockIdx.x * 4 + (threadIdx.x >> 6);
  const int lane = threadIdx.x & 63;
  if (w >= W) return;
  int c[NBKT / 2];  // two 16-bit counts per int (max 2048/bucket < 2^16)
#pragma unroll
  for (int b = 0; b < NBKT / 2; ++b) c[b] = 0;
  const long long base = (long long)w * PW_C;
  for (int r = 0; r < PW_C / 256; ++r) {
    long long e0 = base + r * 256 + lane * 4;
    int bk[4] = {-1, -1, -1, -1};
    if (e0 + 3 < E) {
      i32x4 d = __builtin_nontemporal_load((const i32x4*)(ei + E + e0));
      i32x4 s4 = __builtin_nontemporal_load((const i32x4*)(ei + e0));
#pragma unroll
      for (int k = 0; k < 4; ++k) bk[k] = (d[k] / NPB) * SRCP + s4[k] / SRCW;
    } else {
#pragma unroll
      for (int k = 0; k < 4; ++k)
        if (e0 + k < E) bk[k] = (ei[E + e0 + k] / NPB) * SRCP + ei[e0 + k] / SRCW;
    }
#pragma unroll
    for (int b = 0; b < NBKT; ++b) {
      int t = 0;
#pragma unroll
      for (int k = 0; k < 4; ++k) t += __popcll(__ballot(bk[k] == b));
      c[b >> 1] += t << ((b & 1) * 16);
    }
  }
  if (lane == 0) {
#pragma unroll
    for (int b = 0; b < NBKT; ++b)
      pcnt[w * NBKT + b] = (c[b >> 1] >> ((b & 1) * 16)) & 0xffff;
  }
}

// Per-bucket exclusive scan over waves (one block per bucket).
__global__ void k_pscan(const int* __restrict__ pcnt, int* __restrict__ pbase,
                        int* __restrict__ bt, int W) {
  __shared__ int s[256];
  const int b = blockIdx.x;
  const int t = threadIdx.x;
  const int per = (W + 255) / 256;
  int loc = 0;
  const int w0 = t * per;
  for (int i = 0; i < per; ++i) {
    int w = w0 + i;
    if (w < W) loc += pcnt[w * NBKT + b];
  }
  s[t] = loc;
  __syncthreads();
  for (int off = 1; off < 256; off <<= 1) {
    int u = (t >= off) ? s[t - off] : 0;
    __syncthreads();
    s[t] += u;
    __syncthreads();
  }
  int run = s[t] - loc;  // exclusive
  if (t == 255) bt[b] = s[255];
  for (int i = 0; i < per; ++i) {
    int w = w0 + i;
    if (w < W) {
      pbase[w * NBKT + b] = run;
      run += pcnt[w * NBKT + b];
    }
  }
}

// Absolute bucket bases: partition p contiguous at p*cap, sub-buckets in order.
__global__ void k_sbase(const int* __restrict__ bt, int* __restrict__ bbase,
                        int* __restrict__ bcur, int cap) {
  if (threadIdx.x == 0) {
    for (int p = 0; p < NPART; ++p) {
      int run = 0;
      for (int sb = 0; sb < SRCP; ++sb) {
        bbase[p * SRCP + sb] = p * cap + run;
        run += bt[p * SRCP + sb];
      }
      bcur[p] = run;
    }
  }
}

// Pass B: re-read chunk, write each edge to its exact slot (absolute offsets).
__global__ __launch_bounds__(256) void k_pbin(const int* __restrict__ ei,
                                              const int* __restrict__ pbase,
                                              const int* __restrict__ bbase,
                                              unsigned long long* __restrict__ bkt,
                                              int E, int W) {
  const int w = blockIdx.x * 4 + (threadIdx.x >> 6);
  const int lane = threadIdx.x & 63;
  if (w >= W) return;
  int off[NBKT];
#pragma unroll
  for (int b = 0; b < NBKT; ++b) off[b] = bbase[b] + pbase[w * NBKT + b];
  const unsigned long long lmask = (1ull << lane) - 1ull;
  const long long base = (long long)w * PW_C;
  for (int r = 0; r < PW_C / 256; ++r) {
    long long e0 = base + r * 256 + lane * 4;
    int bk[4] = {-1, -1, -1, -1};
    int sv[4], dv[4];
    if (e0 + 3 < E) {
      i32x4 d = __builtin_nontemporal_load((const i32x4*)(ei + E + e0));
      i32x4 s4 = __builtin_nontemporal_load((const i32x4*)(ei + e0));
#pragma unroll
      for (int k = 0; k < 4; ++k) {
        dv[k] = d[k];
        sv[k] = s4[k];
        bk[k] = (d[k] / NPB) * SRCP + s4[k] / SRCW;
      }
    } else {
#pragma unroll
      for (int k = 0; k < 4; ++k)
        if (e0 + k < E) {
          dv[k] = ei[E + e0 + k];
          sv[k] = ei[e0 + k];
          bk[k] = (dv[k] / NPB) * SRCP + sv[k] / SRCW;
        }
    }
#pragma unroll
    for (int k = 0; k < 4; ++k) {
#pragma unroll
      for (int b = 0; b < NBKT; ++b) {
        unsigned long long m = __ballot(bk[k] == b);
        if (bk[k] == b) {
          int idx = off[b] + __popcll(m & lmask);
          bkt[idx] = ((unsigned long long)(unsigned)dv[k] << 32) | (unsigned)sv[k];
        }
        off[b] += __popcll(m);
      }
    }
  }
}

// Degree histogram per (partition, slice): LDS hist, coalesced slice write.
__global__ __launch_bounds__(256) void k_dhist(
    const unsigned long long* __restrict__ bkt, const int* __restrict__ bcur,
    int cap, int* __restrict__ dhist) {
  __shared__ int hist[NPB];
  const int p = blockIdx.x & (NPART - 1);
  const int b = blockIdx.x >> 3;
  const int tid = threadIdx.x;
  for (int i = tid; i < NPB; i += 256) hist[i] = 0;
  __syncthreads();
  const int n = bcur[p];
  const int chunk = (n + DB - 1) / DB;
  const int lo = b * chunk, hi = min(n, lo + chunk);
  const unsigned long long* base = bkt + (size_t)p * cap;
  const int plo = p * NPB;
  for (int i = lo + tid; i < hi; i += 256) {
    unsigned long long v = base[i];
    atomicAdd(&hist[(int)(v >> 32) - plo], 1);
  }
  __syncthreads();
  int* dst = dhist + ((size_t)p * DB + b) * NPB;
  for (int i = tid; i < NPB; i += 256) dst[i] = hist[i];
}

// In-place exclusive slice-scan of dhist; cnt[i] = total; block sums for scan.
__global__ void k_mergesum(int* __restrict__ dhist, int* __restrict__ cnt,
                           int* __restrict__ bsum, int n) {
  __shared__ int s[256];
  int i = blockIdx.x * 256 + threadIdx.x;
  int acc = 0;
  if (i < n) {
    int p = i / NPB, li = i - p * NPB;
    int* hb = dhist + (size_t)p * DB * NPB + li;
#pragma unroll
    for (int b = 0; b < DB; ++b) {
      int t = hb[b * NPB];
      hb[b * NPB] = acc;
      acc += t;
    }
    cnt[i] = acc;
  }
  s[threadIdx.x] = acc;
  __syncthreads();
  for (int off = 128; off > 0; off >>= 1) {
    if (threadIdx.x < off) s[threadIdx.x] += s[threadIdx.x + off];
    __syncthreads();
  }
  if (threadIdx.x == 0) bsum[blockIdx.x] = s[0];
}

// Fill: ZERO global atomics; slice order preserved -> rows stay src-sorted.
__global__ __launch_bounds__(256) void k_binfill(
    const unsigned long long* __restrict__ bkt, const int* __restrict__ bcur,
    int cap, const int* __restrict__ dhist, const int* __restrict__ row_ptr,
    int* __restrict__ colv) {
  __shared__ int rank[NPB];
  const int p = blockIdx.x & (NPART - 1);
  const int b = blockIdx.x >> 3;
  const int tid = threadIdx.x;
  const int plo = p * NPB;
  const int* soff = dhist + ((size_t)p * DB + b) * NPB;
  for (int li = tid; li < NPB; li += 256) rank[li] = row_ptr[plo + li] + soff[li];
  __syncthreads();
  const int n = bcur[p];
  const int chunk = (n + DB - 1) / DB;
  const int lo = b * chunk, hi = min(n, lo + chunk);
  const unsigned long long* base = bkt + (size_t)p * cap;
  for (int i = lo + tid; i < hi; i += 256) {
    unsigned long long v = base[i];
    int d = (int)(v >> 32);
    int s = (int)(v & 0xffffffffu);
    int pos = atomicAdd(&rank[d - plo], 1);
    colv[pos] = s;
  }
}

__global__ void k_scanb(const int* __restrict__ bsum, int* __restrict__ boff, int nb) {
  __shared__ int s[512];
  int t = threadIdx.x;
  int v = (t < nb) ? bsum[t] : 0;
  s[t] = v;
  __syncthreads();
  for (int off = 1; off < 512; off <<= 1) {
    int u = (t >= off) ? s[t - off] : 0;
    __syncthreads();
    s[t] += u;
    __syncthreads();
  }
  if (t < nb) boff[t] = s[t] - v;  // exclusive block offsets
}

__global__ void k_scatter(const int* __restrict__ cnt, const int* __restrict__ boff,
                          int* __restrict__ row_ptr, int n, int etot) {
  __shared__ int s[256];
  int i = blockIdx.x * 256 + threadIdx.x;
  int v = (i < n) ? cnt[i] : 0;
  s[threadIdx.x] = v;
  __syncthreads();
  for (int off = 1; off < 256; off <<= 1) {
    int u = (threadIdx.x >= off) ? s[threadIdx.x - off] : 0;
    __syncthreads();
    s[threadIdx.x] += u;
    __syncthreads();
  }
  if (i < n) row_ptr[i] = boff[blockIdx.x] + s[threadIdx.x] - v;
  if (i == 0) row_ptr[n] = etot;
}

__global__ void k_nodesc(const int* __restrict__ cnt, float* __restrict__ invd,
                         float* __restrict__ s1v, float* __restrict__ s2v, int n) {
  int i = blockIdx.x * 256 + threadIdx.x;
  if (i >= n) return;
  float degc = fmaxf((float)cnt[i], 1.f);
  invd[i] = 1.f / degc;
  float ld = logf(degc + 1.f);
  s1v[i] = ld * (1.f / AVGLOG);
  s2v[i] = AVGLOG / ld;
}

// W [K][FO] fp32 -> fp16 in MFMA B-fragment order
__global__ void k_wtprep(const float* __restrict__ W, _Float16* __restrict__ Wt,
                         int K, int FO, int FOP) {
  int i = blockIdx.x * 256 + threadIdx.x;
  if (i >= FOP * K) return;
  int nn = i / K, k = i - nn * K;
  float v = (nn < FO) ? W[k * FO + nn] : 0.f;
  int NT = FOP >> 4;
  int kt = k >> 5, q = (k >> 3) & 3, j = k & 7;
  int nt = nn >> 4, m = nn & 15;
  size_t idx = (((size_t)kt * NT + nt) * 64 + (q * 16 + m)) * 8 + j;
  Wt[idx] = (_Float16)v;
}

__global__ void k_xconv(const float* __restrict__ x, _Float16* __restrict__ x16, int n) {
  int i = blockIdx.x * 256 + threadIdx.x;
  if (i < n) x16[i] = (_Float16)x[i];
}

// ---------------- Fused layer: gather/reduce -> LDS (A-frag order) -> MFMA GEMM ----------------
// r5 structure verbatim (866us measured best): full-size s_a, launch_bounds(256,2).
#define MFMA16(a, b, c) __builtin_amdgcn_mfma_f32_16x16x32_f16(a, b, c, 0, 0, 0)

template <int F, int FO, int FOP, bool RELU, bool STATS, typename OT>
__launch_bounds__(256, 2)
__global__ void k_fused(const _Float16* __restrict__ hin,
                        const int* __restrict__ row_ptr, const int* __restrict__ colv,
                        const float* __restrict__ invd,
                        const float* __restrict__ s1g, const float* __restrict__ s2g,
                        const _Float16* __restrict__ Wt, const float* __restrict__ bias,
                        OT* __restrict__ hout, float* __restrict__ csum,
                        float* __restrict__ csq) {
  constexpr int F32 = F / 32;
  constexpr int KTA = F / 8;
  constexpr int NT = FOP / 16;
  constexpr int PPW = (2 * NT) / 4;
  constexpr int XW = F + 8;
  constexpr int SEG = F / 8;   // features per thread (gather)
  constexpr int NP = SEG / 2;  // f16x2 pairs per thread
  __shared__ __align__(16) _Float16 s_x[32][XW];
  __shared__ __align__(16) _Float16 s_a[2 * KTA * 512];
  __shared__ float s_cs[2][FOP];

  const int tid = threadIdx.x;
  const int n0 = blockIdx.x * 32;

  // stage self rows
  for (int idx = tid; idx < 32 * (F / 8); idx += 256) {
    int rr = idx / (F / 8), cc = idx % (F / 8);
    *(f16x8*)&s_x[rr][8 * cc] = *(const f16x8*)&hin[(size_t)(n0 + rr) * F + 8 * cc];
  }
  if (STATS)
    for (int u = tid; u < 2 * FOP; u += 256) (&s_cs[0][0])[u] = 0.f;

  // ---- gather phase ----
  {
    const int r = tid >> 3, g = tid & 7;
    const int n = n0 + r;
    const int e0 = row_ptr[n], e1 = row_ptr[n + 1];
    f32x2 sm[NP], sq[NP];
    f16x2 mn[NP], mx[NP];
    const _Float16 HPI = __builtin_bit_cast(_Float16, (unsigned short)0x7C00);
    const _Float16 HNI = __builtin_bit_cast(_Float16, (unsigned short)0xFC00);
#pragma unroll
    for (int p = 0; p < NP; ++p) {
      sm[p] = (f32x2){0.f, 0.f};
      sq[p] = (f32x2){0.f, 0.f};
      mn[p] = (f16x2){HPI, HPI};
      mx[p] = (f16x2){HNI, HNI};
    }

    auto loadrow = [&](const _Float16* ra, f16x2* pr) {
      if constexpr (SEG % 8 == 0) {
#pragma unroll
        for (int c = 0; c < SEG / 8; ++c) {
          f16x8 v = ((const f16x8*)ra)[c];
          pr[4 * c + 0] = (f16x2){v[0], v[1]};
          pr[4 * c + 1] = (f16x2){v[2], v[3]};
          pr[4 * c + 2] = (f16x2){v[4], v[5]};
          pr[4 * c + 3] = (f16x2){v[6], v[7]};
        }
      } else {
#pragma unroll
        for (int c = 0; c < SEG / 4; ++c) {
          f16x4 v = ((const f16x4*)ra)[c];
          pr[2 * c + 0] = (f16x2){v[0], v[1]};
          pr[2 * c + 1] = (f16x2){v[2], v[3]};
        }
      }
    };
    auto accum = [&](const f16x2* pr) {
#pragma unroll
      for (int p = 0; p < NP; ++p) {
        f32x2 f = __builtin_convertvector(pr[p], f32x2);
        sm[p] += f;
        sq[p] += f * f;
        mn[p] = __builtin_elementwise_min(mn[p], pr[p]);
        mx[p] = __builtin_elementwise_max(mx[p], pr[p]);
      }
    };

    int e = e0;
    for (; e + 1 < e1; e += 2) {
      int c0 = __builtin_nontemporal_load(&colv[e]);
      int c1 = __builtin_nontemporal_load(&colv[e + 1]);
      f16x2 r0[NP], r1[NP];
      loadrow(hin + (size_t)c0 * F + g * SEG, r0);
      loadrow(hin + (size_t)c1 * F + g * SEG, r1);
      accum(r0);
      accum(r1);
    }
    if (e < e1) {
      int c0 = __builtin_nontemporal_load(&colv[e]);
      f16x2 r0[NP];
      loadrow(hin + (size_t)c0 * F + g * SEG, r0);
      accum(r0);
    }

    float iv = invd[n];
    bool has = (e1 > e0);
    const int m = r & 15;
    const int mt = r >> 4;
#pragma unroll
    for (int c = 0; c < SEG / 4; ++c) {
      f16x4 vals[4];
#pragma unroll
      for (int l = 0; l < 4; ++l) {
        int j = 4 * c + l;
        int p = j >> 1, k = j & 1;
        float mean = sm[p][k] * iv;
        float var = sq[p][k] * iv - mean * mean;
        float sd = sqrtf(fmaxf(var, 0.f) + 1e-5f);
        vals[0][l] = (_Float16)mean;
        vals[1][l] = has ? mn[p][k] : (_Float16)0.f;
        vals[2][l] = has ? mx[p][k] : (_Float16)0.f;
        vals[3][l] = (_Float16)sd;
      }
      int f0 = g * SEG + 4 * c;
#pragma unroll
      for (int a = 0; a < 4; ++a) {
        int kk0 = a * F + f0;
        int kt = kk0 >> 5, q = (kk0 >> 3) & 3, j0 = kk0 & 7;
        *(f16x4*)&s_a[((size_t)(mt * KTA + kt)) * 512 + (q * 16 + m) * 8 + j0] = vals[a];
      }
    }
  }
  __syncthreads();

  // ---- MFMA phase ----
  const int w = tid >> 6, ln = tid & 63;
  const int lm = ln & 15, q = ln >> 4;
  const int mt = w & 1;
  const int arow = mt * 16 + lm;
  f32x4 acc0[PPW], acc1[PPW], acc2[PPW];
#pragma unroll
  for (int i = 0; i < PPW; ++i)
#pragma unroll
    for (int t = 0; t < 4; ++t) { acc0[i][t] = 0.f; acc1[i][t] = 0.f; acc2[i][t] = 0.f; }

#pragma unroll
  for (int kt = 0; kt < F32; ++kt) {
    f16x8 a = *(const f16x8*)&s_x[arow][kt * 32 + 8 * q];
#pragma unroll
    for (int i = 0; i < PPW; ++i) {
      int nt = (w >> 1) + 2 * i;
      f16x8 b = *(const f16x8*)&Wt[(((size_t)kt * NT + nt) * 64 + ln) * 8];
      acc0[i] = MFMA16(a, b, acc0[i]);
    }
  }
#pragma unroll
  for (int kt = 0; kt < KTA; ++kt) {
    f16x8 a = *(const f16x8*)&s_a[((size_t)(mt * KTA + kt)) * 512 + ln * 8];
#pragma unroll
    for (int i = 0; i < PPW; ++i) {
      int nt = (w >> 1) + 2 * i;
      f16x8 b0 = *(const f16x8*)&Wt[(((size_t)(F32 + kt) * NT + nt) * 64 + ln) * 8];
      acc0[i] = MFMA16(a, b0, acc0[i]);
      f16x8 b1 = *(const f16x8*)&Wt[(((size_t)(F32 + KTA + kt) * NT + nt) * 64 + ln) * 8];
      acc1[i] = MFMA16(a, b1, acc1[i]);
      f16x8 b2 = *(const f16x8*)&Wt[(((size_t)(F32 + 2 * KTA + kt) * NT + nt) * 64 + ln) * 8];
      acc2[i] = MFMA16(a, b2, acc2[i]);
    }
  }

  float s1r[4], s2r[4];
#pragma unroll
  for (int t = 0; t < 4; ++t) {
    int node = n0 + mt * 16 + q * 4 + t;
    s1r[t] = s1g[node];
    s2r[t] = s2g[node];
  }
#pragma unroll
  for (int i = 0; i < PPW; ++i) {
    int nt = (w >> 1) + 2 * i;
    int ncol = nt * 16 + lm;
    if (FOP == FO || ncol < FO) {
      float bs = bias[ncol];
      float cs = 0.f, cq = 0.f;
#pragma unroll
      for (int t = 0; t < 4; ++t) {
        int node = n0 + mt * 16 + q * 4 + t;
        float v = acc0[i][t] + s1r[t] * acc1[i][t] + s2r[t] * acc2[i][t] + bs;
        if (RELU) v = fmaxf(v, 0.f);
        hout[(size_t)node * FO + ncol] = (OT)v;
        cs += v;
        cq += v * v;
      }
      if (STATS) {
        atomicAdd(&s_cs[0][ncol], cs);
        atomicAdd(&s_cs[1][ncol], cq);
      }
    }
  }
  if (STATS) {
    __syncthreads();
    if (tid < FO) {
      atomicAdd(&csum[tid], s_cs[0][tid]);
      atomicAdd(&csq[tid], s_cs[1][tid]);
    }
  }
}

// ---------------- BN apply ----------------
__global__ void k_bn16(_Float16* __restrict__ h, const float* __restrict__ csum,
                       const float* __restrict__ csq, const float* __restrict__ gg,
                       const float* __restrict__ be, int n, int fo, int relu) {
  int i = blockIdx.x * 256 + threadIdx.x;
  int total = (n * fo) >> 3;
  if (i >= total) return;
  int c0 = (i << 3) % fo;
  float invn = 1.f / (float)n;
  f16x8 v = *(const f16x8*)&h[(size_t)i << 3];
  f16x8 o;
#pragma unroll
  for (int j = 0; j < 8; ++j) {
    int c = c0 + j;
    float mu = csum[c] * invn;
    float var = csq[c] * invn - mu * mu;
    float rs = rsqrtf(var + 1e-5f);
    float x = ((float)v[j] - mu) * rs * gg[c] + be[c];
    if (relu) x = fmaxf(x, 0.f);
    o[j] = (_Float16)x;
  }
  *(f16x8*)&h[(size_t)i << 3] = o;
}

__global__ void k_bnf(float* __restrict__ h, const float* __restrict__ csum,
                      const float* __restrict__ csq, const float* __restrict__ gg,
                      const float* __restrict__ be, int n, int fo, int relu) {
  int i = blockIdx.x * 256 + threadIdx.x;
  if (i >= n * fo) return;
  int c = i % fo;
  float invn = 1.f / (float)n;
  float mu = csum[c] * invn;
  float var = csq[c] * invn - mu * mu;
  float rs = rsqrtf(var + 1e-5f);
  float v = (h[i] - mu) * rs * gg[c] + be[c];
  if (relu) v = fmaxf(v, 0.f);
  h[i] = v;
}

// ---------------- pooling + head ----------------
__global__ void k_pool(const float* __restrict__ h, const int* __restrict__ batch,
                       float* __restrict__ zsum, float* __restrict__ gcnt, int n) {
  __shared__ float sv[NGRAPH * 20];
  __shared__ float sc[NGRAPH];
  int tid = threadIdx.x;
  for (int u = tid; u < NGRAPH * 20; u += 256) sv[u] = 0.f;
  if (tid < NGRAPH) sc[tid] = 0.f;
  __syncthreads();
  int i = blockIdx.x * 256 + tid;
  if (i < n) {
    int g = batch[i];
    atomicAdd(&sc[g], 1.f);
    for (int j = 0; j < 20; ++j) atomicAdd(&sv[g * 20 + j], h[(size_t)i * 20 + j]);
  }
  __syncthreads();
  if (tid < NGRAPH && sc[tid] != 0.f) {
    atomicAdd(&gcnt[tid], sc[tid]);
    for (int j = 0; j < 20; ++j) atomicAdd(&zsum[tid * 20 + j], sv[tid * 20 + j]);
  }
}

__global__ void k_head(const float* __restrict__ zsum, const float* __restrict__ gcnt,
                       const float* __restrict__ wl, const float* __restrict__ bl,
                       float* __restrict__ out) {
  int g = threadIdx.x;
  if (g >= NGRAPH) return;
  float z[20];
  float icg = 1.f / fmaxf(gcnt[g], 1.f);
#pragma unroll
  for (int j = 0; j < 20; ++j) {
    z[j] = zsum[g * 20 + j] * icg;
    out[NGRAPH * 11 + g * 20 + j] = z[j];  // second output: z
  }
  float lo[11];
#pragma unroll
  for (int o = 0; o < 11; ++o) {
    float a = bl[o];
    for (int j = 0; j < 20; ++j) a += z[j] * wl[j * 11 + o];
    lo[o] = a;
  }
  float m = lo[0];
  for (int o = 1; o < 11; ++o) m = fmaxf(m, lo[o]);
  float s = 0.f;
  for (int o = 0; o < 11; ++o) { lo[o] = expf(lo[o] - m); s += lo[o]; }
  float is = 1.f / s;
  for (int o = 0; o < 11; ++o) out[g * 11 + o] = lo[o] * is;  // first output: softmax
}

// ---------------- launch ----------------
static inline char* carve(char*& p, size_t bytes) {
  char* r = p;
  p += (bytes + 255) & ~(size_t)255;
  return r;
}

extern "C" void kernel_launch(void* const* d_in, const int* in_sizes, int n_in,
                              void* d_out, int out_size, void* d_ws, size_t ws_size,
                              hipStream_t stream) {
  const float* x = (const float*)d_in[0];
  const int* ei = (const int*)d_in[1];
  const int* batch = (const int*)d_in[2];
  const float* W0 = (const float*)d_in[3];
  const float* b0 = (const float*)d_in[4];
  const float* W1 = (const float*)d_in[5];
  const float* b1 = (const float*)d_in[6];
  const float* W2 = (const float*)d_in[7];
  const float* b2 = (const float*)d_in[8];
  const float* W3 = (const float*)d_in[9];
  const float* b3 = (const float*)d_in[10];
  const float* g0 = (const float*)d_in[11];
  const float* be0 = (const float*)d_in[12];
  const float* g1 = (const float*)d_in[13];
  const float* be1 = (const float*)d_in[14];
  const float* g2 = (const float*)d_in[15];
  const float* be2 = (const float*)d_in[16];
  const float* wl = (const float*)d_in[17];
  const float* bl = (const float*)d_in[18];
  float* out = (float*)d_out;

  const int E = in_sizes[1] / 2;       // 3200000
  const int NB = (NN + 255) / 256;     // 391
  const int BCAP = E / NPART + 65536;  // per-partition capacity
  const int W = (E + PW_C - 1) / PW_C; // waves for binning
  const int GB = (W + 3) / 4;          // blocks (4 waves each)

  char* p = (char*)d_ws;
  int* cnt = (int*)carve(p, (size_t)NN * 4);
  int* row_ptr = (int*)carve(p, (size_t)(NN + 1) * 4);
  int* bsum = (int*)carve(p, 2048);
  int* boff = (int*)carve(p, 2048);
  int* bcur = (int*)carve(p, 256);
  int* bt = (int*)carve(p, 512);
  int* bbase = (int*)carve(p, 512);
  int* pcnt = (int*)carve(p, (size_t)W * NBKT * 4);
  int* pbase = (int*)carve(p, (size_t)W * NBKT * 4);
  int* colv = (int*)carve(p, (size_t)E * 4);
  unsigned long long* bkt = (unsigned long long*)carve(p, (size_t)NPART * BCAP * 8);
  int* dhist = (int*)carve(p, (size_t)NPART * DB * NPB * 4);
  float* invd = (float*)carve(p, (size_t)NN * 4);
  float* s1v = (float*)carve(p, (size_t)NN * 4);
  float* s2v = (float*)carve(p, (size_t)NN * 4);
  _Float16* Wt0 = (_Float16*)carve(p, (size_t)96 * 832 * 2);
  _Float16* Wt1 = (_Float16*)carve(p, (size_t)64 * 1248 * 2);
  _Float16* Wt2 = (_Float16*)carve(p, (size_t)32 * 832 * 2);
  _Float16* Wt3 = (_Float16*)carve(p, (size_t)32 * 416 * 2);
  float* cs = (float*)carve(p, 192 * 4);
  float* csum = cs;
  float* csq = cs + 96;
  float* pacc = (float*)carve(p, (NGRAPH * 20 + NGRAPH) * 4);
  float* zsum = pacc;
  float* gcnt = pacc + NGRAPH * 20;
  _Float16* x16 = (_Float16*)carve(p, (size_t)NN * 64 * 2);
  _Float16* hA16 = (_Float16*)carve(p, (size_t)NN * 96 * 2);
  _Float16* hB16 = (_Float16*)carve(p, (size_t)NN * 96 * 2);
  float* h3 = (float*)x16;  // reuse: x16 dead after L0

  // CSR: 64-bucket (dst,src-octile) binning -> src-sorted colv rows
  hipMemsetAsync(pacc, 0, (NGRAPH * 20 + NGRAPH) * 4, stream);
  k_pcnt<<<GB, 256, 0, stream>>>(ei, pcnt, E, W);
  k_pscan<<<NBKT, 256, 0, stream>>>(pcnt, pbase, bt, W);
  k_sbase<<<1, 64, 0, stream>>>(bt, bbase, bcur, BCAP);
  k_pbin<<<GB, 256, 0, stream>>>(ei, pbase, bbase, bkt, E, W);
  k_dhist<<<NPART * DB, 256, 0, stream>>>(bkt, bcur, BCAP, dhist);
  k_mergesum<<<NB, 256, 0, stream>>>(dhist, cnt, bsum, NN);
  k_scanb<<<1, 512, 0, stream>>>(bsum, boff, NB);
  k_scatter<<<NB, 256, 0, stream>>>(cnt, boff, row_ptr, NN, E);
  k_nodesc<<<NB, 256, 0, stream>>>(cnt, invd, s1v, s2v, NN);
  k_binfill<<<NPART * DB, 256, 0, stream>>>(bkt, bcur, BCAP, dhist, row_ptr, colv);

  // fp16 swizzled weights + fp16 x
  k_wtprep<<<(96 * 832 + 255) / 256, 256, 0, stream>>>(W0, Wt0, 832, 96, 96);
  k_wtprep<<<(64 * 1248 + 255) / 256, 256, 0, stream>>>(W1, Wt1, 1248, 64, 64);
  k_wtprep<<<(32 * 832 + 255) / 256, 256, 0, stream>>>(W2, Wt2, 832, 32, 32);
  k_wtprep<<<(32 * 416 + 255) / 256, 256, 0, stream>>>(W3, Wt3, 416, 20, 32);
  k_xconv<<<(NN * 64 + 255) / 256, 256, 0, stream>>>(x, x16, NN * 64);

  const int GP = NN / 32;  // 3125

  // Layer 0: (64 -> 96), BN + ReLU (stats fused)
  hipMemsetAsync(cs, 0, 192 * 4, stream);
  k_fused<64, 96, 96, false, true, _Float16><<<GP, 256, 0, stream>>>(
      x16, row_ptr, colv, invd, s1v, s2v, Wt0, b0, hA16, csum, csq);
  k_bn16<<<(NN * 96 / 8 + 255) / 256, 256, 0, stream>>>(hA16, csum, csq, g0, be0, NN, 96, 1);

  // Layer 1: (96 -> 64), BN + ReLU
  hipMemsetAsync(cs, 0, 192 * 4, stream);
  k_fused<96, 64, 64, false, true, _Float16><<<GP, 256, 0, stream>>>(
      hA16, row_ptr, colv, invd, s1v, s2v, Wt1, b1, hB16, csum, csq);
  k_bn16<<<(NN * 64 / 8 + 255) / 256, 256, 0, stream>>>(hB16, csum, csq, g1, be1, NN, 64, 1);

  // Layer 2: (64 -> 32), ReLU fused, no BN
  k_fused<64, 32, 32, true, false, _Float16><<<GP, 256, 0, stream>>>(
      hB16, row_ptr, colv, invd, s1v, s2v, Wt2, b2, hA16, csum, csq);

  // Layer 3: (32 -> 20), BN (no ReLU), fp32 out
  hipMemsetAsync(cs, 0, 192 * 4, stream);
  k_fused<32, 20, 32, false, true, float><<<GP, 256, 0, stream>>>(
      hA16, row_ptr, colv, invd, s1v, s2v, Wt3, b3, h3, csum, csq);
  k_bnf<<<(NN * 20 + 255) / 256, 256, 0, stream>>>(h3, csum, csq, g2, be2, NN, 20, 0);

  // global mean pool + linear + softmax
  k_pool<<<NB, 256, 0, stream>>>(h3, batch, zsum, gcnt, NN);
  k_head<<<1, 64, 0, stream>>>(zsum, gcnt, wl, bl, out);
}

// Round 11
// 808.200 us; speedup vs baseline: 1.1366x; 1.1366x over previous
//
#include <hip/hip_runtime.h>

#define NN 100000
#define NGRAPH 64
#define NPART 8
#define SRCP 4
#define SRCW 25000
#define NBKT 32  // (dstpart, srcpart) buckets
#define NPB 12500
#define DB 16
#define PW_C 2048
#define AVGLOG 3.4965075614664802f

using f32x2 = __attribute__((ext_vector_type(2))) float;
using f32x4 = __attribute__((ext_vector_type(4))) float;
using f16x2 = __attribute__((ext_vector_type(2))) _Float16;
using f16x8 = __attribute__((ext_vector_type(8))) _Float16;
using f16x4 = __attribute__((ext_vector_type(4))) _Float16;
using i32x4 = __attribute__((ext_vector_type(4))) int;

// ---------------- CSR build ----------------
// Wave-synchronous two-pass binning over 32 (dst,src-quartile) buckets.
// Src sub-bucketing makes colv rows src-sorted -> gather walks the h-table
// in a moving window with L2/L3 reuse. (SRCP=8 measured worse: binning cost
// doubles, FETCH gain <2% -- r10.)
__global__ __launch_bounds__(256) void k_pcnt(const int* __restrict__ ei,
                                              int* __restrict__ pcnt, int E, int W) {
  const int w = blockIdx.x * 4 + (threadIdx.x >> 6);
  const int lane = threadIdx.x & 63;
  if (w >= W) return;
  int c[NBKT];
#pragma unroll
  for (int b = 0; b < NBKT; ++b) c[b] = 0;
  const long long base = (long long)w * PW_C;
  for (int r = 0; r < PW_C / 256; ++r) {
    long long e0 = base + r * 256 + lane * 4;
    int bk[4] = {-1, -1, -1, -1};
    if (e0 + 3 < E) {
      i32x4 d = __builtin_nontemporal_load((const i32x4*)(ei + E + e0));
      i32x4 s4 = __builtin_nontemporal_load((const i32x4*)(ei + e0));
#pragma unroll
      for (int k = 0; k < 4; ++k) bk[k] = (d[k] / NPB) * SRCP + s4[k] / SRCW;
    } else {
#pragma unroll
      for (int k = 0; k < 4; ++k)
        if (e0 + k < E) bk[k] = (ei[E + e0 + k] / NPB) * SRCP + ei[e0 + k] / SRCW;
    }
#pragma unroll
    for (int b = 0; b < NBKT; ++b) {
      int t = 0;
#pragma unroll
      for (int k = 0; k < 4; ++k) t += __popcll(__ballot(bk[k] == b));
      c[b] += t;
    }
  }
  if (lane == 0) {
#pragma unroll
    for (int b = 0; b < NBKT; ++b) pcnt[w * NBKT + b] = c[b];
  }
}

// Per-bucket exclusive scan over waves (one block per bucket).
__global__ void k_pscan(const int* __restrict__ pcnt, int* __restrict__ pbase,
                        int* __restrict__ bt, int W) {
  __shared__ int s[256];
  const int b = blockIdx.x;
  const int t = threadIdx.x;
  const int per = (W + 255) / 256;
  int loc = 0;
  const int w0 = t * per;
  for (int i = 0; i < per; ++i) {
    int w = w0 + i;
    if (w < W) loc += pcnt[w * NBKT + b];
  }
  s[t] = loc;
  __syncthreads();
  for (int off = 1; off < 256; off <<= 1) {
    int u = (t >= off) ? s[t - off] : 0;
    __syncthreads();
    s[t] += u;
    __syncthreads();
  }
  int run = s[t] - loc;  // exclusive
  if (t == 255) bt[b] = s[255];
  for (int i = 0; i < per; ++i) {
    int w = w0 + i;
    if (w < W) {
      pbase[w * NBKT + b] = run;
      run += pcnt[w * NBKT + b];
    }
  }
}

// Absolute bucket bases: partition p contiguous at p*cap, sub-buckets in order.
__global__ void k_sbase(const int* __restrict__ bt, int* __restrict__ bbase,
                        int* __restrict__ bcur, int cap) {
  if (threadIdx.x == 0) {
    for (int p = 0; p < NPART; ++p) {
      int run = 0;
      for (int sb = 0; sb < SRCP; ++sb) {
        bbase[p * SRCP + sb] = p * cap + run;
        run += bt[p * SRCP + sb];
      }
      bcur[p] = run;
    }
  }
}

// Pass B: re-read chunk, write each edge to its exact slot (absolute offsets).
__global__ __launch_bounds__(256) void k_pbin(const int* __restrict__ ei,
                                              const int* __restrict__ pbase,
                                              const int* __restrict__ bbase,
                                              unsigned long long* __restrict__ bkt,
                                              int E, int W) {
  const int w = blockIdx.x * 4 + (threadIdx.x >> 6);
  const int lane = threadIdx.x & 63;
  if (w >= W) return;
  int off[NBKT];
#pragma unroll
  for (int b = 0; b < NBKT; ++b) off[b] = bbase[b] + pbase[w * NBKT + b];
  const unsigned long long lmask = (1ull << lane) - 1ull;
  const long long base = (long long)w * PW_C;
  for (int r = 0; r < PW_C / 256; ++r) {
    long long e0 = base + r * 256 + lane * 4;
    int bk[4] = {-1, -1, -1, -1};
    int sv[4], dv[4];
    if (e0 + 3 < E) {
      i32x4 d = __builtin_nontemporal_load((const i32x4*)(ei + E + e0));
      i32x4 s4 = __builtin_nontemporal_load((const i32x4*)(ei + e0));
#pragma unroll
      for (int k = 0; k < 4; ++k) {
        dv[k] = d[k];
        sv[k] = s4[k];
        bk[k] = (d[k] / NPB) * SRCP + s4[k] / SRCW;
      }
    } else {
#pragma unroll
      for (int k = 0; k < 4; ++k)
        if (e0 + k < E) {
          dv[k] = ei[E + e0 + k];
          sv[k] = ei[e0 + k];
          bk[k] = (dv[k] / NPB) * SRCP + sv[k] / SRCW;
        }
    }
#pragma unroll
    for (int k = 0; k < 4; ++k) {
#pragma unroll
      for (int b = 0; b < NBKT; ++b) {
        unsigned long long m = __ballot(bk[k] == b);
        if (bk[k] == b) {
          int idx = off[b] + __popcll(m & lmask);
          bkt[idx] = ((unsigned long long)(unsigned)dv[k] << 32) | (unsigned)sv[k];
        }
        off[b] += __popcll(m);
      }
    }
  }
}

// Degree histogram per (partition, slice): LDS hist, coalesced slice write.
__global__ __launch_bounds__(256) void k_dhist(
    const unsigned long long* __restrict__ bkt, const int* __restrict__ bcur,
    int cap, int* __restrict__ dhist) {
  __shared__ int hist[NPB];
  const int p = blockIdx.x & (NPART - 1);
  const int b = blockIdx.x >> 3;
  const int tid = threadIdx.x;
  for (int i = tid; i < NPB; i += 256) hist[i] = 0;
  __syncthreads();
  const int n = bcur[p];
  const int chunk = (n + DB - 1) / DB;
  const int lo = b * chunk, hi = min(n, lo + chunk);
  const unsigned long long* base = bkt + (size_t)p * cap;
  const int plo = p * NPB;
  for (int i = lo + tid; i < hi; i += 256) {
    unsigned long long v = base[i];
    atomicAdd(&hist[(int)(v >> 32) - plo], 1);
  }
  __syncthreads();
  int* dst = dhist + ((size_t)p * DB + b) * NPB;
  for (int i = tid; i < NPB; i += 256) dst[i] = hist[i];
}

// In-place exclusive slice-scan of dhist; cnt[i] = total; block sums for scan.
__global__ void k_mergesum(int* __restrict__ dhist, int* __restrict__ cnt,
                           int* __restrict__ bsum, int n) {
  __shared__ int s[256];
  int i = blockIdx.x * 256 + threadIdx.x;
  int acc = 0;
  if (i < n) {
    int p = i / NPB, li = i - p * NPB;
    int* hb = dhist + (size_t)p * DB * NPB + li;
#pragma unroll
    for (int b = 0; b < DB; ++b) {
      int t = hb[b * NPB];
      hb[b * NPB] = acc;
      acc += t;
    }
    cnt[i] = acc;
  }
  s[threadIdx.x] = acc;
  __syncthreads();
  for (int off = 128; off > 0; off >>= 1) {
    if (threadIdx.x < off) s[threadIdx.x] += s[threadIdx.x + off];
    __syncthreads();
  }
  if (threadIdx.x == 0) bsum[blockIdx.x] = s[0];
}

// Fill: ZERO global atomics; slice order preserved -> rows stay src-sorted.
__global__ __launch_bounds__(256) void k_binfill(
    const unsigned long long* __restrict__ bkt, const int* __restrict__ bcur,
    int cap, const int* __restrict__ dhist, const int* __restrict__ row_ptr,
    int* __restrict__ colv) {
  __shared__ int rank[NPB];
  const int p = blockIdx.x & (NPART - 1);
  const int b = blockIdx.x >> 3;
  const int tid = threadIdx.x;
  const int plo = p * NPB;
  const int* soff = dhist + ((size_t)p * DB + b) * NPB;
  for (int li = tid; li < NPB; li += 256) rank[li] = row_ptr[plo + li] + soff[li];
  __syncthreads();
  const int n = bcur[p];
  const int chunk = (n + DB - 1) / DB;
  const int lo = b * chunk, hi = min(n, lo + chunk);
  const unsigned long long* base = bkt + (size_t)p * cap;
  for (int i = lo + tid; i < hi; i += 256) {
    unsigned long long v = base[i];
    int d = (int)(v >> 32);
    int s = (int)(v & 0xffffffffu);
    int pos = atomicAdd(&rank[d - plo], 1);
    colv[pos] = s;
  }
}

__global__ void k_scanb(const int* __restrict__ bsum, int* __restrict__ boff, int nb) {
  __shared__ int s[512];
  int t = threadIdx.x;
  int v = (t < nb) ? bsum[t] : 0;
  s[t] = v;
  __syncthreads();
  for (int off = 1; off < 512; off <<= 1) {
    int u = (t >= off) ? s[t - off] : 0;
    __syncthreads();
    s[t] += u;
    __syncthreads();
  }
  if (t < nb) boff[t] = s[t] - v;  // exclusive block offsets
}

__global__ void k_scatter(const int* __restrict__ cnt, const int* __restrict__ boff,
                          int* __restrict__ row_ptr, int n, int etot) {
  __shared__ int s[256];
  int i = blockIdx.x * 256 + threadIdx.x;
  int v = (i < n) ? cnt[i] : 0;
  s[threadIdx.x] = v;
  __syncthreads();
  for (int off = 1; off < 256; off <<= 1) {
    int u = (threadIdx.x >= off) ? s[threadIdx.x - off] : 0;
    __syncthreads();
    s[threadIdx.x] += u;
    __syncthreads();
  }
  if (i < n) row_ptr[i] = boff[blockIdx.x] + s[threadIdx.x] - v;
  if (i == 0) row_ptr[n] = etot;
}

__global__ void k_nodesc(const int* __restrict__ cnt, float* __restrict__ invd,
                         float* __restrict__ s1v, float* __restrict__ s2v, int n) {
  int i = blockIdx.x * 256 + threadIdx.x;
  if (i >= n) return;
  float degc = fmaxf((float)cnt[i], 1.f);
  invd[i] = 1.f / degc;
  float ld = logf(degc + 1.f);
  s1v[i] = ld * (1.f / AVGLOG);
  s2v[i] = AVGLOG / ld;
}

// W [K][FO] fp32 -> fp16 in MFMA B-fragment order
__global__ void k_wtprep(const float* __restrict__ W, _Float16* __restrict__ Wt,
                         int K, int FO, int FOP) {
  int i = blockIdx.x * 256 + threadIdx.x;
  if (i >= FOP * K) return;
  int nn = i / K, k = i - nn * K;
  float v = (nn < FO) ? W[k * FO + nn] : 0.f;
  int NT = FOP >> 4;
  int kt = k >> 5, q = (k >> 3) & 3, j = k & 7;
  int nt = nn >> 4, m = nn & 15;
  size_t idx = (((size_t)kt * NT + nt) * 64 + (q * 16 + m)) * 8 + j;
  Wt[idx] = (_Float16)v;
}

__global__ void k_xconv(const float* __restrict__ x, _Float16* __restrict__ x16, int n) {
  int i = blockIdx.x * 256 + threadIdx.x;
  if (i < n) x16[i] = (_Float16)x[i];
}

// ---------------- Fused layer: gather/reduce -> LDS (A-frag order) -> MFMA GEMM ----------------
// r5 LDS/MFMA structure (measured best); gather upgraded to 4-edge unroll for
// memory-level parallelism (valid now: no NT stores in fused path, src-sorted
// colv keeps the 4 rows in one L2 window).
#define MFMA16(a, b, c) __builtin_amdgcn_mfma_f32_16x16x32_f16(a, b, c, 0, 0, 0)

template <int F, int FO, int FOP, bool RELU, bool STATS, typename OT>
__launch_bounds__(256, 2)
__global__ void k_fused(const _Float16* __restrict__ hin,
                        const int* __restrict__ row_ptr, const int* __restrict__ colv,
                        const float* __restrict__ invd,
                        const float* __restrict__ s1g, const float* __restrict__ s2g,
                        const _Float16* __restrict__ Wt, const float* __restrict__ bias,
                        OT* __restrict__ hout, float* __restrict__ csum,
                        float* __restrict__ csq) {
  constexpr int F32 = F / 32;
  constexpr int KTA = F / 8;
  constexpr int NT = FOP / 16;
  constexpr int PPW = (2 * NT) / 4;
  constexpr int XW = F + 8;
  constexpr int SEG = F / 8;   // features per thread (gather)
  constexpr int NP = SEG / 2;  // f16x2 pairs per thread
  __shared__ __align__(16) _Float16 s_x[32][XW];
  __shared__ __align__(16) _Float16 s_a[2 * KTA * 512];
  __shared__ float s_cs[2][FOP];

  const int tid = threadIdx.x;
  const int n0 = blockIdx.x * 32;

  // stage self rows
  for (int idx = tid; idx < 32 * (F / 8); idx += 256) {
    int rr = idx / (F / 8), cc = idx % (F / 8);
    *(f16x8*)&s_x[rr][8 * cc] = *(const f16x8*)&hin[(size_t)(n0 + rr) * F + 8 * cc];
  }
  if (STATS)
    for (int u = tid; u < 2 * FOP; u += 256) (&s_cs[0][0])[u] = 0.f;

  // ---- gather phase ----
  {
    const int r = tid >> 3, g = tid & 7;
    const int n = n0 + r;
    const int e0 = row_ptr[n], e1 = row_ptr[n + 1];
    f32x2 sm[NP], sq[NP];
    f16x2 mn[NP], mx[NP];
    const _Float16 HPI = __builtin_bit_cast(_Float16, (unsigned short)0x7C00);
    const _Float16 HNI = __builtin_bit_cast(_Float16, (unsigned short)0xFC00);
#pragma unroll
    for (int p = 0; p < NP; ++p) {
      sm[p] = (f32x2){0.f, 0.f};
      sq[p] = (f32x2){0.f, 0.f};
      mn[p] = (f16x2){HPI, HPI};
      mx[p] = (f16x2){HNI, HNI};
    }

    auto loadrow = [&](const _Float16* ra, f16x2* pr) {
      if constexpr (SEG % 8 == 0) {
#pragma unroll
        for (int c = 0; c < SEG / 8; ++c) {
          f16x8 v = ((const f16x8*)ra)[c];
          pr[4 * c + 0] = (f16x2){v[0], v[1]};
          pr[4 * c + 1] = (f16x2){v[2], v[3]};
          pr[4 * c + 2] = (f16x2){v[4], v[5]};
          pr[4 * c + 3] = (f16x2){v[6], v[7]};
        }
      } else {
#pragma unroll
        for (int c = 0; c < SEG / 4; ++c) {
          f16x4 v = ((const f16x4*)ra)[c];
          pr[2 * c + 0] = (f16x2){v[0], v[1]};
          pr[2 * c + 1] = (f16x2){v[2], v[3]};
        }
      }
    };
    auto accum = [&](const f16x2* pr) {
#pragma unroll
      for (int p = 0; p < NP; ++p) {
        f32x2 f = __builtin_convertvector(pr[p], f32x2);
        sm[p] += f;
        sq[p] += f * f;
        mn[p] = __builtin_elementwise_min(mn[p], pr[p]);
        mx[p] = __builtin_elementwise_max(mx[p], pr[p]);
      }
    };

    int e = e0;
    for (; e + 3 < e1; e += 4) {
      int c0 = __builtin_nontemporal_load(&colv[e + 0]);
      int c1 = __builtin_nontemporal_load(&colv[e + 1]);
      int c2 = __builtin_nontemporal_load(&colv[e + 2]);
      int c3 = __builtin_nontemporal_load(&colv[e + 3]);
      f16x2 r0[NP], r1[NP], r2[NP], r3[NP];
      loadrow(hin + (size_t)c0 * F + g * SEG, r0);
      loadrow(hin + (size_t)c1 * F + g * SEG, r1);
      loadrow(hin + (size_t)c2 * F + g * SEG, r2);
      loadrow(hin + (size_t)c3 * F + g * SEG, r3);
      accum(r0);
      accum(r1);
      accum(r2);
      accum(r3);
    }
    for (; e < e1; ++e) {
      int c0 = __builtin_nontemporal_load(&colv[e]);
      f16x2 r0[NP];
      loadrow(hin + (size_t)c0 * F + g * SEG, r0);
      accum(r0);
    }

    float iv = invd[n];
    bool has = (e1 > e0);
    const int m = r & 15;
    const int mt = r >> 4;
#pragma unroll
    for (int c = 0; c < SEG / 4; ++c) {
      f16x4 vals[4];
#pragma unroll
      for (int l = 0; l < 4; ++l) {
        int j = 4 * c + l;
        int p = j >> 1, k = j & 1;
        float mean = sm[p][k] * iv;
        float var = sq[p][k] * iv - mean * mean;
        float sd = sqrtf(fmaxf(var, 0.f) + 1e-5f);
        vals[0][l] = (_Float16)mean;
        vals[1][l] = has ? mn[p][k] : (_Float16)0.f;
        vals[2][l] = has ? mx[p][k] : (_Float16)0.f;
        vals[3][l] = (_Float16)sd;
      }
      int f0 = g * SEG + 4 * c;
#pragma unroll
      for (int a = 0; a < 4; ++a) {
        int kk0 = a * F + f0;
        int kt = kk0 >> 5, q = (kk0 >> 3) & 3, j0 = kk0 & 7;
        *(f16x4*)&s_a[((size_t)(mt * KTA + kt)) * 512 + (q * 16 + m) * 8 + j0] = vals[a];
      }
    }
  }
  __syncthreads();

  // ---- MFMA phase ----
  const int w = tid >> 6, ln = tid & 63;
  const int lm = ln & 15, q = ln >> 4;
  const int mt = w & 1;
  const int arow = mt * 16 + lm;
  f32x4 acc0[PPW], acc1[PPW], acc2[PPW];
#pragma unroll
  for (int i = 0; i < PPW; ++i)
#pragma unroll
    for (int t = 0; t < 4; ++t) { acc0[i][t] = 0.f; acc1[i][t] = 0.f; acc2[i][t] = 0.f; }

#pragma unroll
  for (int kt = 0; kt < F32; ++kt) {
    f16x8 a = *(const f16x8*)&s_x[arow][kt * 32 + 8 * q];
#pragma unroll
    for (int i = 0; i < PPW; ++i) {
      int nt = (w >> 1) + 2 * i;
      f16x8 b = *(const f16x8*)&Wt[(((size_t)kt * NT + nt) * 64 + ln) * 8];
      acc0[i] = MFMA16(a, b, acc0[i]);
    }
  }
#pragma unroll
  for (int kt = 0; kt < KTA; ++kt) {
    f16x8 a = *(const f16x8*)&s_a[((size_t)(mt * KTA + kt)) * 512 + ln * 8];
#pragma unroll
    for (int i = 0; i < PPW; ++i) {
      int nt = (w >> 1) + 2 * i;
      f16x8 b0 = *(const f16x8*)&Wt[(((size_t)(F32 + kt) * NT + nt) * 64 + ln) * 8];
      acc0[i] = MFMA16(a, b0, acc0[i]);
      f16x8 b1 = *(const f16x8*)&Wt[(((size_t)(F32 + KTA + kt) * NT + nt) * 64 + ln) * 8];
      acc1[i] = MFMA16(a, b1, acc1[i]);
      f16x8 b2 = *(const f16x8*)&Wt[(((size_t)(F32 + 2 * KTA + kt) * NT + nt) * 64 + ln) * 8];
      acc2[i] = MFMA16(a, b2, acc2[i]);
    }
  }

  float s1r[4], s2r[4];
#pragma unroll
  for (int t = 0; t < 4; ++t) {
    int node = n0 + mt * 16 + q * 4 + t;
    s1r[t] = s1g[node];
    s2r[t] = s2g[node];
  }
#pragma unroll
  for (int i = 0; i < PPW; ++i) {
    int nt = (w >> 1) + 2 * i;
    int ncol = nt * 16 + lm;
    if (FOP == FO || ncol < FO) {
      float bs = bias[ncol];
      float cs = 0.f, cq = 0.f;
#pragma unroll
      for (int t = 0; t < 4; ++t) {
        int node = n0 + mt * 16 + q * 4 + t;
        float v = acc0[i][t] + s1r[t] * acc1[i][t] + s2r[t] * acc2[i][t] + bs;
        if (RELU) v = fmaxf(v, 0.f);
        hout[(size_t)node * FO + ncol] = (OT)v;
        cs += v;
        cq += v * v;
      }
      if (STATS) {
        atomicAdd(&s_cs[0][ncol], cs);
        atomicAdd(&s_cs[1][ncol], cq);
      }
    }
  }
  if (STATS) {
    __syncthreads();
    if (tid < FO) {
      atomicAdd(&csum[tid], s_cs[0][tid]);
      atomicAdd(&csq[tid], s_cs[1][tid]);
    }
  }
}

// ---------------- BN apply ----------------
__global__ void k_bn16(_Float16* __restrict__ h, const float* __restrict__ csum,
                       const float* __restrict__ csq, const float* __restrict__ gg,
                       const float* __restrict__ be, int n, int fo, int relu) {
  int i = blockIdx.x * 256 + threadIdx.x;
  int total = (n * fo) >> 3;
  if (i >= total) return;
  int c0 = (i << 3) % fo;
  float invn = 1.f / (float)n;
  f16x8 v = *(const f16x8*)&h[(size_t)i << 3];
  f16x8 o;
#pragma unroll
  for (int j = 0; j < 8; ++j) {
    int c = c0 + j;
    float mu = csum[c] * invn;
    float var = csq[c] * invn - mu * mu;
    float rs = rsqrtf(var + 1e-5f);
    float x = ((float)v[j] - mu) * rs * gg[c] + be[c];
    if (relu) x = fmaxf(x, 0.f);
    o[j] = (_Float16)x;
  }
  *(f16x8*)&h[(size_t)i << 3] = o;
}

__global__ void k_bnf(float* __restrict__ h, const float* __restrict__ csum,
                      const float* __restrict__ csq, const float* __restrict__ gg,
                      const float* __restrict__ be, int n, int fo, int relu) {
  int i = blockIdx.x * 256 + threadIdx.x;
  if (i >= n * fo) return;
  int c = i % fo;
  float invn = 1.f / (float)n;
  float mu = csum[c] * invn;
  float var = csq[c] * invn - mu * mu;
  float rs = rsqrtf(var + 1e-5f);
  float v = (h[i] - mu) * rs * gg[c] + be[c];
  if (relu) v = fmaxf(v, 0.f);
  h[i] = v;
}

// ---------------- pooling + head ----------------
__global__ void k_pool(const float* __restrict__ h, const int* __restrict__ batch,
                       float* __restrict__ zsum, float* __restrict__ gcnt, int n) {
  __shared__ float sv[NGRAPH * 20];
  __shared__ float sc[NGRAPH];
  int tid = threadIdx.x;
  for (int u = tid; u < NGRAPH * 20; u += 256) sv[u] = 0.f;
  if (tid < NGRAPH) sc[tid] = 0.f;
  __syncthreads();
  int i = blockIdx.x * 256 + tid;
  if (i < n) {
    int g = batch[i];
    atomicAdd(&sc[g], 1.f);
    for (int j = 0; j < 20; ++j) atomicAdd(&sv[g * 20 + j], h[(size_t)i * 20 + j]);
  }
  __syncthreads();
  if (tid < NGRAPH && sc[tid] != 0.f) {
    atomicAdd(&gcnt[tid], sc[tid]);
    for (int j = 0; j < 20; ++j) atomicAdd(&zsum[tid * 20 + j], sv[tid * 20 + j]);
  }
}

__global__ void k_head(const float* __restrict__ zsum, const float* __restrict__ gcnt,
                       const float* __restrict__ wl, const float* __restrict__ bl,
                       float* __restrict__ out) {
  int g = threadIdx.x;
  if (g >= NGRAPH) return;
  float z[20];
  float icg = 1.f / fmaxf(gcnt[g], 1.f);
#pragma unroll
  for (int j = 0; j < 20; ++j) {
    z[j] = zsum[g * 20 + j] * icg;
    out[NGRAPH * 11 + g * 20 + j] = z[j];  // second output: z
  }
  float lo[11];
#pragma unroll
  for (int o = 0; o < 11; ++o) {
    float a = bl[o];
    for (int j = 0; j < 20; ++j) a += z[j] * wl[j * 11 + o];
    lo[o] = a;
  }
  float m = lo[0];
  for (int o = 1; o < 11; ++o) m = fmaxf(m, lo[o]);
  float s = 0.f;
  for (int o = 0; o < 11; ++o) { lo[o] = expf(lo[o] - m); s += lo[o]; }
  float is = 1.f / s;
  for (int o = 0; o < 11; ++o) out[g * 11 + o] = lo[o] * is;  // first output: softmax
}

// ---------------- launch ----------------
static inline char* carve(char*& p, size_t bytes) {
  char* r = p;
  p += (bytes + 255) & ~(size_t)255;
  return r;
}

extern "C" void kernel_launch(void* const* d_in, const int* in_sizes, int n_in,
                              void* d_out, int out_size, void* d_ws, size_t ws_size,
                              hipStream_t stream) {
  const float* x = (const float*)d_in[0];
  const int* ei = (const int*)d_in[1];
  const int* batch = (const int*)d_in[2];
  const float* W0 = (const float*)d_in[3];
  const float* b0 = (const float*)d_in[4];
  const float* W1 = (const float*)d_in[5];
  const float* b1 = (const float*)d_in[6];
  const float* W2 = (const float*)d_in[7];
  const float* b2 = (const float*)d_in[8];
  const float* W3 = (const float*)d_in[9];
  const float* b3 = (const float*)d_in[10];
  const float* g0 = (const float*)d_in[11];
  const float* be0 = (const float*)d_in[12];
  const float* g1 = (const float*)d_in[13];
  const float* be1 = (const float*)d_in[14];
  const float* g2 = (const float*)d_in[15];
  const float* be2 = (const float*)d_in[16];
  const float* wl = (const float*)d_in[17];
  const float* bl = (const float*)d_in[18];
  float* out = (float*)d_out;

  const int E = in_sizes[1] / 2;       // 3200000
  const int NB = (NN + 255) / 256;     // 391
  const int BCAP = E / NPART + 65536;  // per-partition capacity
  const int W = (E + PW_C - 1) / PW_C; // waves for binning
  const int GB = (W + 3) / 4;          // blocks (4 waves each)

  char* p = (char*)d_ws;
  int* cnt = (int*)carve(p, (size_t)NN * 4);
  int* row_ptr = (int*)carve(p, (size_t)(NN + 1) * 4);
  int* bsum = (int*)carve(p, 2048);
  int* boff = (int*)carve(p, 2048);
  int* bcur = (int*)carve(p, 256);
  int* bt = (int*)carve(p, 256);
  int* bbase = (int*)carve(p, 256);
  int* pcnt = (int*)carve(p, (size_t)W * NBKT * 4);
  int* pbase = (int*)carve(p, (size_t)W * NBKT * 4);
  int* colv = (int*)carve(p, (size_t)E * 4);
  unsigned long long* bkt = (unsigned long long*)carve(p, (size_t)NPART * BCAP * 8);
  int* dhist = (int*)carve(p, (size_t)NPART * DB * NPB * 4);
  float* invd = (float*)carve(p, (size_t)NN * 4);
  float* s1v = (float*)carve(p, (size_t)NN * 4);
  float* s2v = (float*)carve(p, (size_t)NN * 4);
  _Float16* Wt0 = (_Float16*)carve(p, (size_t)96 * 832 * 2);
  _Float16* Wt1 = (_Float16*)carve(p, (size_t)64 * 1248 * 2);
  _Float16* Wt2 = (_Float16*)carve(p, (size_t)32 * 832 * 2);
  _Float16* Wt3 = (_Float16*)carve(p, (size_t)32 * 416 * 2);
  float* cs = (float*)carve(p, 192 * 4);
  float* csum = cs;
  float* csq = cs + 96;
  float* pacc = (float*)carve(p, (NGRAPH * 20 + NGRAPH) * 4);
  float* zsum = pacc;
  float* gcnt = pacc + NGRAPH * 20;
  _Float16* x16 = (_Float16*)carve(p, (size_t)NN * 64 * 2);
  _Float16* hA16 = (_Float16*)carve(p, (size_t)NN * 96 * 2);
  _Float16* hB16 = (_Float16*)carve(p, (size_t)NN * 96 * 2);
  float* h3 = (float*)x16;  // reuse: x16 dead after L0

  // CSR: 32-bucket (dst,src-quartile) binning -> src-sorted colv rows
  hipMemsetAsync(pacc, 0, (NGRAPH * 20 + NGRAPH) * 4, stream);
  k_pcnt<<<GB, 256, 0, stream>>>(ei, pcnt, E, W);
  k_pscan<<<NBKT, 256, 0, stream>>>(pcnt, pbase, bt, W);
  k_sbase<<<1, 64, 0, stream>>>(bt, bbase, bcur, BCAP);
  k_pbin<<<GB, 256, 0, stream>>>(ei, pbase, bbase, bkt, E, W);
  k_dhist<<<NPART * DB, 256, 0, stream>>>(bkt, bcur, BCAP, dhist);
  k_mergesum<<<NB, 256, 0, stream>>>(dhist, cnt, bsum, NN);
  k_scanb<<<1, 512, 0, stream>>>(bsum, boff, NB);
  k_scatter<<<NB, 256, 0, stream>>>(cnt, boff, row_ptr, NN, E);
  k_nodesc<<<NB, 256, 0, stream>>>(cnt, invd, s1v, s2v, NN);
  k_binfill<<<NPART * DB, 256, 0, stream>>>(bkt, bcur, BCAP, dhist, row_ptr, colv);

  // fp16 swizzled weights + fp16 x
  k_wtprep<<<(96 * 832 + 255) / 256, 256, 0, stream>>>(W0, Wt0, 832, 96, 96);
  k_wtprep<<<(64 * 1248 + 255) / 256, 256, 0, stream>>>(W1, Wt1, 1248, 64, 64);
  k_wtprep<<<(32 * 832 + 255) / 256, 256, 0, stream>>>(W2, Wt2, 832, 32, 32);
  k_wtprep<<<(32 * 416 + 255) / 256, 256, 0, stream>>>(W3, Wt3, 416, 20, 32);
  k_xconv<<<(NN * 64 + 255) / 256, 256, 0, stream>>>(x, x16, NN * 64);

  const int GP = NN / 32;  // 3125

  // Layer 0: (64 -> 96), BN + ReLU (stats fused)
  hipMemsetAsync(cs, 0, 192 * 4, stream);
  k_fused<64, 96, 96, false, true, _Float16><<<GP, 256, 0, stream>>>(
      x16, row_ptr, colv, invd, s1v, s2v, Wt0, b0, hA16, csum, csq);
  k_bn16<<<(NN * 96 / 8 + 255) / 256, 256, 0, stream>>>(hA16, csum, csq, g0, be0, NN, 96, 1);

  // Layer 1: (96 -> 64), BN + ReLU
  hipMemsetAsync(cs, 0, 192 * 4, stream);
  k_fused<96, 64, 64, false, true, _Float16><<<GP, 256, 0, stream>>>(
      hA16, row_ptr, colv, invd, s1v, s2v, Wt1, b1, hB16, csum, csq);
  k_bn16<<<(NN * 64 / 8 + 255) / 256, 256, 0, stream>>>(hB16, csum, csq, g1, be1, NN, 64, 1);

  // Layer 2: (64 -> 32), ReLU fused, no BN
  k_fused<64, 32, 32, true, false, _Float16><<<GP, 256, 0, stream>>>(
      hB16, row_ptr, colv, invd, s1v, s2v, Wt2, b2, hA16, csum, csq);

  // Layer 3: (32 -> 20), BN (no ReLU), fp32 out
  hipMemsetAsync(cs, 0, 192 * 4, stream);
  k_fused<32, 20, 32, false, true, float><<<GP, 256, 0, stream>>>(
      hA16, row_ptr, colv, invd, s1v, s2v, Wt3, b3, h3, csum, csq);
  k_bnf<<<(NN * 20 + 255) / 256, 256, 0, stream>>>(h3, csum, csq, g2, be2, NN, 20, 0);

  // global mean pool + linear + softmax
  k_pool<<<NB, 256, 0, stream>>>(h3, batch, zsum, gcnt, NN);
  k_head<<<1, 64, 0, stream>>>(zsum, gcnt, wl, bl, out);
}

// Round 12
// 776.326 us; speedup vs baseline: 1.1833x; 1.0411x over previous
//
#include <hip/hip_runtime.h>

#define NN 100000
#define NGRAPH 64
#define NPART 8
#define SRCP 4
#define SRCW 25000
#define NBKT 32  // (dstpart, srcpart) buckets
#define NPB 12500
#define DB 16
#define PW_C 2048
#define AVGLOG 3.4965075614664802f

using f32x2 = __attribute__((ext_vector_type(2))) float;
using f32x4 = __attribute__((ext_vector_type(4))) float;
using f16x2 = __attribute__((ext_vector_type(2))) _Float16;
using f16x8 = __attribute__((ext_vector_type(8))) _Float16;
using f16x4 = __attribute__((ext_vector_type(4))) _Float16;
using i32x4 = __attribute__((ext_vector_type(4))) int;

// ---------------- CSR build ----------------
// Wave-synchronous two-pass binning over 32 (dst,src-quartile) buckets.
// Src sub-bucketing makes colv rows src-sorted -> gather walks the h-table
// in a moving window with L2/L3 reuse. (SRCP=8 measured worse -- r10.)
__global__ __launch_bounds__(256) void k_pcnt(const int* __restrict__ ei,
                                              int* __restrict__ pcnt, int E, int W) {
  const int w = blockIdx.x * 4 + (threadIdx.x >> 6);
  const int lane = threadIdx.x & 63;
  if (w >= W) return;
  int c[NBKT];
#pragma unroll
  for (int b = 0; b < NBKT; ++b) c[b] = 0;
  const long long base = (long long)w * PW_C;
  for (int r = 0; r < PW_C / 256; ++r) {
    long long e0 = base + r * 256 + lane * 4;
    int bk[4] = {-1, -1, -1, -1};
    if (e0 + 3 < E) {
      i32x4 d = __builtin_nontemporal_load((const i32x4*)(ei + E + e0));
      i32x4 s4 = __builtin_nontemporal_load((const i32x4*)(ei + e0));
#pragma unroll
      for (int k = 0; k < 4; ++k) bk[k] = (d[k] / NPB) * SRCP + s4[k] / SRCW;
    } else {
#pragma unroll
      for (int k = 0; k < 4; ++k)
        if (e0 + k < E) bk[k] = (ei[E + e0 + k] / NPB) * SRCP + ei[e0 + k] / SRCW;
    }
#pragma unroll
    for (int b = 0; b < NBKT; ++b) {
      int t = 0;
#pragma unroll
      for (int k = 0; k < 4; ++k) t += __popcll(__ballot(bk[k] == b));
      c[b] += t;
    }
  }
  if (lane == 0) {
#pragma unroll
    for (int b = 0; b < NBKT; ++b) pcnt[w * NBKT + b] = c[b];
  }
}

// Per-bucket exclusive scan over waves (one block per bucket).
__global__ void k_pscan(const int* __restrict__ pcnt, int* __restrict__ pbase,
                        int* __restrict__ bt, int W) {
  __shared__ int s[256];
  const int b = blockIdx.x;
  const int t = threadIdx.x;
  const int per = (W + 255) / 256;
  int loc = 0;
  const int w0 = t * per;
  for (int i = 0; i < per; ++i) {
    int w = w0 + i;
    if (w < W) loc += pcnt[w * NBKT + b];
  }
  s[t] = loc;
  __syncthreads();
  for (int off = 1; off < 256; off <<= 1) {
    int u = (t >= off) ? s[t - off] : 0;
    __syncthreads();
    s[t] += u;
    __syncthreads();
  }
  int run = s[t] - loc;  // exclusive
  if (t == 255) bt[b] = s[255];
  for (int i = 0; i < per; ++i) {
    int w = w0 + i;
    if (w < W) {
      pbase[w * NBKT + b] = run;
      run += pcnt[w * NBKT + b];
    }
  }
}

// Absolute bucket bases: partition p contiguous at p*cap, sub-buckets in order.
__global__ void k_sbase(const int* __restrict__ bt, int* __restrict__ bbase,
                        int* __restrict__ bcur, int cap) {
  if (threadIdx.x == 0) {
    for (int p = 0; p < NPART; ++p) {
      int run = 0;
      for (int sb = 0; sb < SRCP; ++sb) {
        bbase[p * SRCP + sb] = p * cap + run;
        run += bt[p * SRCP + sb];
      }
      bcur[p] = run;
    }
  }
}

// Pass B: re-read chunk, write each edge to its exact slot (absolute offsets).
__global__ __launch_bounds__(256) void k_pbin(const int* __restrict__ ei,
                                              const int* __restrict__ pbase,
                                              const int* __restrict__ bbase,
                                              unsigned long long* __restrict__ bkt,
                                              int E, int W) {
  const int w = blockIdx.x * 4 + (threadIdx.x >> 6);
  const int lane = threadIdx.x & 63;
  if (w >= W) return;
  int off[NBKT];
#pragma unroll
  for (int b = 0; b < NBKT; ++b) off[b] = bbase[b] + pbase[w * NBKT + b];
  const unsigned long long lmask = (1ull << lane) - 1ull;
  const long long base = (long long)w * PW_C;
  for (int r = 0; r < PW_C / 256; ++r) {
    long long e0 = base + r * 256 + lane * 4;
    int bk[4] = {-1, -1, -1, -1};
    int sv[4], dv[4];
    if (e0 + 3 < E) {
      i32x4 d = __builtin_nontemporal_load((const i32x4*)(ei + E + e0));
      i32x4 s4 = __builtin_nontemporal_load((const i32x4*)(ei + e0));
#pragma unroll
      for (int k = 0; k < 4; ++k) {
        dv[k] = d[k];
        sv[k] = s4[k];
        bk[k] = (d[k] / NPB) * SRCP + s4[k] / SRCW;
      }
    } else {
#pragma unroll
      for (int k = 0; k < 4; ++k)
        if (e0 + k < E) {
          dv[k] = ei[E + e0 + k];
          sv[k] = ei[e0 + k];
          bk[k] = (dv[k] / NPB) * SRCP + sv[k] / SRCW;
        }
    }
#pragma unroll
    for (int k = 0; k < 4; ++k) {
#pragma unroll
      for (int b = 0; b < NBKT; ++b) {
        unsigned long long m = __ballot(bk[k] == b);
        if (bk[k] == b) {
          int idx = off[b] + __popcll(m & lmask);
          bkt[idx] = ((unsigned long long)(unsigned)dv[k] << 32) | (unsigned)sv[k];
        }
        off[b] += __popcll(m);
      }
    }
  }
}

// Degree histogram per (partition, slice): LDS hist, coalesced slice write.
__global__ __launch_bounds__(256) void k_dhist(
    const unsigned long long* __restrict__ bkt, const int* __restrict__ bcur,
    int cap, int* __restrict__ dhist) {
  __shared__ int hist[NPB];
  const int p = blockIdx.x & (NPART - 1);
  const int b = blockIdx.x >> 3;
  const int tid = threadIdx.x;
  for (int i = tid; i < NPB; i += 256) hist[i] = 0;
  __syncthreads();
  const int n = bcur[p];
  const int chunk = (n + DB - 1) / DB;
  const int lo = b * chunk, hi = min(n, lo + chunk);
  const unsigned long long* base = bkt + (size_t)p * cap;
  const int plo = p * NPB;
  for (int i = lo + tid; i < hi; i += 256) {
    unsigned long long v = base[i];
    atomicAdd(&hist[(int)(v >> 32) - plo], 1);
  }
  __syncthreads();
  int* dst = dhist + ((size_t)p * DB + b) * NPB;
  for (int i = tid; i < NPB; i += 256) dst[i] = hist[i];
}

// In-place exclusive slice-scan of dhist; cnt[i] = total; block sums for scan.
__global__ void k_mergesum(int* __restrict__ dhist, int* __restrict__ cnt,
                           int* __restrict__ bsum, int n) {
  __shared__ int s[256];
  int i = blockIdx.x * 256 + threadIdx.x;
  int acc = 0;
  if (i < n) {
    int p = i / NPB, li = i - p * NPB;
    int* hb = dhist + (size_t)p * DB * NPB + li;
#pragma unroll
    for (int b = 0; b < DB; ++b) {
      int t = hb[b * NPB];
      hb[b * NPB] = acc;
      acc += t;
    }
    cnt[i] = acc;
  }
  s[threadIdx.x] = acc;
  __syncthreads();
  for (int off = 128; off > 0; off >>= 1) {
    if (threadIdx.x < off) s[threadIdx.x] += s[threadIdx.x + off];
    __syncthreads();
  }
  if (threadIdx.x == 0) bsum[blockIdx.x] = s[0];
}

// Fill: ZERO global atomics; slice order preserved -> rows stay src-sorted.
__global__ __launch_bounds__(256) void k_binfill(
    const unsigned long long* __restrict__ bkt, const int* __restrict__ bcur,
    int cap, const int* __restrict__ dhist, const int* __restrict__ row_ptr,
    int* __restrict__ colv) {
  __shared__ int rank[NPB];
  const int p = blockIdx.x & (NPART - 1);
  const int b = blockIdx.x >> 3;
  const int tid = threadIdx.x;
  const int plo = p * NPB;
  const int* soff = dhist + ((size_t)p * DB + b) * NPB;
  for (int li = tid; li < NPB; li += 256) rank[li] = row_ptr[plo + li] + soff[li];
  __syncthreads();
  const int n = bcur[p];
  const int chunk = (n + DB - 1) / DB;
  const int lo = b * chunk, hi = min(n, lo + chunk);
  const unsigned long long* base = bkt + (size_t)p * cap;
  for (int i = lo + tid; i < hi; i += 256) {
    unsigned long long v = base[i];
    int d = (int)(v >> 32);
    int s = (int)(v & 0xffffffffu);
    int pos = atomicAdd(&rank[d - plo], 1);
    colv[pos] = s;
  }
}

__global__ void k_scanb(const int* __restrict__ bsum, int* __restrict__ boff, int nb) {
  __shared__ int s[512];
  int t = threadIdx.x;
  int v = (t < nb) ? bsum[t] : 0;
  s[t] = v;
  __syncthreads();
  for (int off = 1; off < 512; off <<= 1) {
    int u = (t >= off) ? s[t - off] : 0;
    __syncthreads();
    s[t] += u;
    __syncthreads();
  }
  if (t < nb) boff[t] = s[t] - v;  // exclusive block offsets
}

__global__ void k_scatter(const int* __restrict__ cnt, const int* __restrict__ boff,
                          int* __restrict__ row_ptr, int n, int etot) {
  __shared__ int s[256];
  int i = blockIdx.x * 256 + threadIdx.x;
  int v = (i < n) ? cnt[i] : 0;
  s[threadIdx.x] = v;
  __syncthreads();
  for (int off = 1; off < 256; off <<= 1) {
    int u = (threadIdx.x >= off) ? s[threadIdx.x - off] : 0;
    __syncthreads();
    s[threadIdx.x] += u;
    __syncthreads();
  }
  if (i < n) row_ptr[i] = boff[blockIdx.x] + s[threadIdx.x] - v;
  if (i == 0) row_ptr[n] = etot;
}

__global__ void k_nodesc(const int* __restrict__ cnt, float* __restrict__ invd,
                         float* __restrict__ s1v, float* __restrict__ s2v, int n) {
  int i = blockIdx.x * 256 + threadIdx.x;
  if (i >= n) return;
  float degc = fmaxf((float)cnt[i], 1.f);
  invd[i] = 1.f / degc;
  float ld = logf(degc + 1.f);
  s1v[i] = ld * (1.f / AVGLOG);
  s2v[i] = AVGLOG / ld;
}

// W [K][FO] fp32 -> fp16 in MFMA B-fragment order
__global__ void k_wtprep(const float* __restrict__ W, _Float16* __restrict__ Wt,
                         int K, int FO, int FOP) {
  int i = blockIdx.x * 256 + threadIdx.x;
  if (i >= FOP * K) return;
  int nn = i / K, k = i - nn * K;
  float v = (nn < FO) ? W[k * FO + nn] : 0.f;
  int NT = FOP >> 4;
  int kt = k >> 5, q = (k >> 3) & 3, j = k & 7;
  int nt = nn >> 4, m = nn & 15;
  size_t idx = (((size_t)kt * NT + nt) * 64 + (q * 16 + m)) * 8 + j;
  Wt[idx] = (_Float16)v;
}

__global__ void k_xconv(const float* __restrict__ x, _Float16* __restrict__ x16, int n) {
  int i = blockIdx.x * 256 + threadIdx.x;
  if (i < n) x16[i] = (_Float16)x[i];
}

// ---------------- Fused layer: gather/reduce -> LDS (A-frag order) -> MFMA GEMM ----------------
// r5 LDS/MFMA structure; gather with 8-edge unroll (2x r11's MLP -- each thread
// keeps ~24 loads in flight to hide L2-miss/L3 latency; src-sorted colv keeps
// all 8 rows in one L2 window).
#define MFMA16(a, b, c) __builtin_amdgcn_mfma_f32_16x16x32_f16(a, b, c, 0, 0, 0)

template <int F, int FO, int FOP, bool RELU, bool STATS, typename OT>
__launch_bounds__(256, 2)
__global__ void k_fused(const _Float16* __restrict__ hin,
                        const int* __restrict__ row_ptr, const int* __restrict__ colv,
                        const float* __restrict__ invd,
                        const float* __restrict__ s1g, const float* __restrict__ s2g,
                        const _Float16* __restrict__ Wt, const float* __restrict__ bias,
                        OT* __restrict__ hout, float* __restrict__ csum,
                        float* __restrict__ csq) {
  constexpr int F32 = F / 32;
  constexpr int KTA = F / 8;
  constexpr int NT = FOP / 16;
  constexpr int PPW = (2 * NT) / 4;
  constexpr int XW = F + 8;
  constexpr int SEG = F / 8;   // features per thread (gather)
  constexpr int NP = SEG / 2;  // f16x2 pairs per thread
  __shared__ __align__(16) _Float16 s_x[32][XW];
  __shared__ __align__(16) _Float16 s_a[2 * KTA * 512];
  __shared__ float s_cs[2][FOP];

  const int tid = threadIdx.x;
  const int n0 = blockIdx.x * 32;

  // stage self rows
  for (int idx = tid; idx < 32 * (F / 8); idx += 256) {
    int rr = idx / (F / 8), cc = idx % (F / 8);
    *(f16x8*)&s_x[rr][8 * cc] = *(const f16x8*)&hin[(size_t)(n0 + rr) * F + 8 * cc];
  }
  if (STATS)
    for (int u = tid; u < 2 * FOP; u += 256) (&s_cs[0][0])[u] = 0.f;

  // ---- gather phase ----
  {
    const int r = tid >> 3, g = tid & 7;
    const int n = n0 + r;
    const int e0 = row_ptr[n], e1 = row_ptr[n + 1];
    f32x2 sm[NP], sq[NP];
    f16x2 mn[NP], mx[NP];
    const _Float16 HPI = __builtin_bit_cast(_Float16, (unsigned short)0x7C00);
    const _Float16 HNI = __builtin_bit_cast(_Float16, (unsigned short)0xFC00);
#pragma unroll
    for (int p = 0; p < NP; ++p) {
      sm[p] = (f32x2){0.f, 0.f};
      sq[p] = (f32x2){0.f, 0.f};
      mn[p] = (f16x2){HPI, HPI};
      mx[p] = (f16x2){HNI, HNI};
    }

    auto loadrow = [&](const _Float16* ra, f16x2* pr) {
      if constexpr (SEG % 8 == 0) {
#pragma unroll
        for (int c = 0; c < SEG / 8; ++c) {
          f16x8 v = ((const f16x8*)ra)[c];
          pr[4 * c + 0] = (f16x2){v[0], v[1]};
          pr[4 * c + 1] = (f16x2){v[2], v[3]};
          pr[4 * c + 2] = (f16x2){v[4], v[5]};
          pr[4 * c + 3] = (f16x2){v[6], v[7]};
        }
      } else {
#pragma unroll
        for (int c = 0; c < SEG / 4; ++c) {
          f16x4 v = ((const f16x4*)ra)[c];
          pr[2 * c + 0] = (f16x2){v[0], v[1]};
          pr[2 * c + 1] = (f16x2){v[2], v[3]};
        }
      }
    };
    auto accum = [&](const f16x2* pr) {
#pragma unroll
      for (int p = 0; p < NP; ++p) {
        f32x2 f = __builtin_convertvector(pr[p], f32x2);
        sm[p] += f;
        sq[p] += f * f;
        mn[p] = __builtin_elementwise_min(mn[p], pr[p]);
        mx[p] = __builtin_elementwise_max(mx[p], pr[p]);
      }
    };

    int e = e0;
    for (; e + 7 < e1; e += 8) {
      int c0 = __builtin_nontemporal_load(&colv[e + 0]);
      int c1 = __builtin_nontemporal_load(&colv[e + 1]);
      int c2 = __builtin_nontemporal_load(&colv[e + 2]);
      int c3 = __builtin_nontemporal_load(&colv[e + 3]);
      int c4 = __builtin_nontemporal_load(&colv[e + 4]);
      int c5 = __builtin_nontemporal_load(&colv[e + 5]);
      int c6 = __builtin_nontemporal_load(&colv[e + 6]);
      int c7 = __builtin_nontemporal_load(&colv[e + 7]);
      f16x2 r0[NP], r1[NP], r2[NP], r3[NP], r4[NP], r5[NP], r6[NP], r7[NP];
      loadrow(hin + (size_t)c0 * F + g * SEG, r0);
      loadrow(hin + (size_t)c1 * F + g * SEG, r1);
      loadrow(hin + (size_t)c2 * F + g * SEG, r2);
      loadrow(hin + (size_t)c3 * F + g * SEG, r3);
      loadrow(hin + (size_t)c4 * F + g * SEG, r4);
      loadrow(hin + (size_t)c5 * F + g * SEG, r5);
      loadrow(hin + (size_t)c6 * F + g * SEG, r6);
      loadrow(hin + (size_t)c7 * F + g * SEG, r7);
      accum(r0);
      accum(r1);
      accum(r2);
      accum(r3);
      accum(r4);
      accum(r5);
      accum(r6);
      accum(r7);
    }
    for (; e + 1 < e1; e += 2) {
      int c0 = __builtin_nontemporal_load(&colv[e]);
      int c1 = __builtin_nontemporal_load(&colv[e + 1]);
      f16x2 r0[NP], r1[NP];
      loadrow(hin + (size_t)c0 * F + g * SEG, r0);
      loadrow(hin + (size_t)c1 * F + g * SEG, r1);
      accum(r0);
      accum(r1);
    }
    if (e < e1) {
      int c0 = __builtin_nontemporal_load(&colv[e]);
      f16x2 r0[NP];
      loadrow(hin + (size_t)c0 * F + g * SEG, r0);
      accum(r0);
    }

    float iv = invd[n];
    bool has = (e1 > e0);
    const int m = r & 15;
    const int mt = r >> 4;
#pragma unroll
    for (int c = 0; c < SEG / 4; ++c) {
      f16x4 vals[4];
#pragma unroll
      for (int l = 0; l < 4; ++l) {
        int j = 4 * c + l;
        int p = j >> 1, k = j & 1;
        float mean = sm[p][k] * iv;
        float var = sq[p][k] * iv - mean * mean;
        float sd = sqrtf(fmaxf(var, 0.f) + 1e-5f);
        vals[0][l] = (_Float16)mean;
        vals[1][l] = has ? mn[p][k] : (_Float16)0.f;
        vals[2][l] = has ? mx[p][k] : (_Float16)0.f;
        vals[3][l] = (_Float16)sd;
      }
      int f0 = g * SEG + 4 * c;
#pragma unroll
      for (int a = 0; a < 4; ++a) {
        int kk0 = a * F + f0;
        int kt = kk0 >> 5, q = (kk0 >> 3) & 3, j0 = kk0 & 7;
        *(f16x4*)&s_a[((size_t)(mt * KTA + kt)) * 512 + (q * 16 + m) * 8 + j0] = vals[a];
      }
    }
  }
  __syncthreads();

  // ---- MFMA phase ----
  const int w = tid >> 6, ln = tid & 63;
  const int lm = ln & 15, q = ln >> 4;
  const int mt = w & 1;
  const int arow = mt * 16 + lm;
  f32x4 acc0[PPW], acc1[PPW], acc2[PPW];
#pragma unroll
  for (int i = 0; i < PPW; ++i)
#pragma unroll
    for (int t = 0; t < 4; ++t) { acc0[i][t] = 0.f; acc1[i][t] = 0.f; acc2[i][t] = 0.f; }

#pragma unroll
  for (int kt = 0; kt < F32; ++kt) {
    f16x8 a = *(const f16x8*)&s_x[arow][kt * 32 + 8 * q];
#pragma unroll
    for (int i = 0; i < PPW; ++i) {
      int nt = (w >> 1) + 2 * i;
      f16x8 b = *(const f16x8*)&Wt[(((size_t)kt * NT + nt) * 64 + ln) * 8];
      acc0[i] = MFMA16(a, b, acc0[i]);
    }
  }
#pragma unroll
  for (int kt = 0; kt < KTA; ++kt) {
    f16x8 a = *(const f16x8*)&s_a[((size_t)(mt * KTA + kt)) * 512 + ln * 8];
#pragma unroll
    for (int i = 0; i < PPW; ++i) {
      int nt = (w >> 1) + 2 * i;
      f16x8 b0 = *(const f16x8*)&Wt[(((size_t)(F32 + kt) * NT + nt) * 64 + ln) * 8];
      acc0[i] = MFMA16(a, b0, acc0[i]);
      f16x8 b1 = *(const f16x8*)&Wt[(((size_t)(F32 + KTA + kt) * NT + nt) * 64 + ln) * 8];
      acc1[i] = MFMA16(a, b1, acc1[i]);
      f16x8 b2 = *(const f16x8*)&Wt[(((size_t)(F32 + 2 * KTA + kt) * NT + nt) * 64 + ln) * 8];
      acc2[i] = MFMA16(a, b2, acc2[i]);
    }
  }

  float s1r[4], s2r[4];
#pragma unroll
  for (int t = 0; t < 4; ++t) {
    int node = n0 + mt * 16 + q * 4 + t;
    s1r[t] = s1g[node];
    s2r[t] = s2g[node];
  }
#pragma unroll
  for (int i = 0; i < PPW; ++i) {
    int nt = (w >> 1) + 2 * i;
    int ncol = nt * 16 + lm;
    if (FOP == FO || ncol < FO) {
      float bs = bias[ncol];
      float cs = 0.f, cq = 0.f;
#pragma unroll
      for (int t = 0; t < 4; ++t) {
        int node = n0 + mt * 16 + q * 4 + t;
        float v = acc0[i][t] + s1r[t] * acc1[i][t] + s2r[t] * acc2[i][t] + bs;
        if (RELU) v = fmaxf(v, 0.f);
        hout[(size_t)node * FO + ncol] = (OT)v;
        cs += v;
        cq += v * v;
      }
      if (STATS) {
        atomicAdd(&s_cs[0][ncol], cs);
        atomicAdd(&s_cs[1][ncol], cq);
      }
    }
  }
  if (STATS) {
    __syncthreads();
    if (tid < FO) {
      atomicAdd(&csum[tid], s_cs[0][tid]);
      atomicAdd(&csq[tid], s_cs[1][tid]);
    }
  }
}

// ---------------- BN apply ----------------
__global__ void k_bn16(_Float16* __restrict__ h, const float* __restrict__ csum,
                       const float* __restrict__ csq, const float* __restrict__ gg,
                       const float* __restrict__ be, int n, int fo, int relu) {
  int i = blockIdx.x * 256 + threadIdx.x;
  int total = (n * fo) >> 3;
  if (i >= total) return;
  int c0 = (i << 3) % fo;
  float invn = 1.f / (float)n;
  f16x8 v = *(const f16x8*)&h[(size_t)i << 3];
  f16x8 o;
#pragma unroll
  for (int j = 0; j < 8; ++j) {
    int c = c0 + j;
    float mu = csum[c] * invn;
    float var = csq[c] * invn - mu * mu;
    float rs = rsqrtf(var + 1e-5f);
    float x = ((float)v[j] - mu) * rs * gg[c] + be[c];
    if (relu) x = fmaxf(x, 0.f);
    o[j] = (_Float16)x;
  }
  *(f16x8*)&h[(size_t)i << 3] = o;
}

__global__ void k_bnf(float* __restrict__ h, const float* __restrict__ csum,
                      const float* __restrict__ csq, const float* __restrict__ gg,
                      const float* __restrict__ be, int n, int fo, int relu) {
  int i = blockIdx.x * 256 + threadIdx.x;
  if (i >= n * fo) return;
  int c = i % fo;
  float invn = 1.f / (float)n;
  float mu = csum[c] * invn;
  float var = csq[c] * invn - mu * mu;
  float rs = rsqrtf(var + 1e-5f);
  float v = (h[i] - mu) * rs * gg[c] + be[c];
  if (relu) v = fmaxf(v, 0.f);
  h[i] = v;
}

// ---------------- pooling + head ----------------
__global__ void k_pool(const float* __restrict__ h, const int* __restrict__ batch,
                       float* __restrict__ zsum, float* __restrict__ gcnt, int n) {
  __shared__ float sv[NGRAPH * 20];
  __shared__ float sc[NGRAPH];
  int tid = threadIdx.x;
  for (int u = tid; u < NGRAPH * 20; u += 256) sv[u] = 0.f;
  if (tid < NGRAPH) sc[tid] = 0.f;
  __syncthreads();
  int i = blockIdx.x * 256 + tid;
  if (i < n) {
    int g = batch[i];
    atomicAdd(&sc[g], 1.f);
    for (int j = 0; j < 20; ++j) atomicAdd(&sv[g * 20 + j], h[(size_t)i * 20 + j]);
  }
  __syncthreads();
  if (tid < NGRAPH && sc[tid] != 0.f) {
    atomicAdd(&gcnt[tid], sc[tid]);
    for (int j = 0; j < 20; ++j) atomicAdd(&zsum[tid * 20 + j], sv[tid * 20 + j]);
  }
}

__global__ void k_head(const float* __restrict__ zsum, const float* __restrict__ gcnt,
                       const float* __restrict__ wl, const float* __restrict__ bl,
                       float* __restrict__ out) {
  int g = threadIdx.x;
  if (g >= NGRAPH) return;
  float z[20];
  float icg = 1.f / fmaxf(gcnt[g], 1.f);
#pragma unroll
  for (int j = 0; j < 20; ++j) {
    z[j] = zsum[g * 20 + j] * icg;
    out[NGRAPH * 11 + g * 20 + j] = z[j];  // second output: z
  }
  float lo[11];
#pragma unroll
  for (int o = 0; o < 11; ++o) {
    float a = bl[o];
    for (int j = 0; j < 20; ++j) a += z[j] * wl[j * 11 + o];
    lo[o] = a;
  }
  float m = lo[0];
  for (int o = 1; o < 11; ++o) m = fmaxf(m, lo[o]);
  float s = 0.f;
  for (int o = 0; o < 11; ++o) { lo[o] = expf(lo[o] - m); s += lo[o]; }
  float is = 1.f / s;
  for (int o = 0; o < 11; ++o) out[g * 11 + o] = lo[o] * is;  // first output: softmax
}

// ---------------- launch ----------------
static inline char* carve(char*& p, size_t bytes) {
  char* r = p;
  p += (bytes + 255) & ~(size_t)255;
  return r;
}

extern "C" void kernel_launch(void* const* d_in, const int* in_sizes, int n_in,
                              void* d_out, int out_size, void* d_ws, size_t ws_size,
                              hipStream_t stream) {
  const float* x = (const float*)d_in[0];
  const int* ei = (const int*)d_in[1];
  const int* batch = (const int*)d_in[2];
  const float* W0 = (const float*)d_in[3];
  const float* b0 = (const float*)d_in[4];
  const float* W1 = (const float*)d_in[5];
  const float* b1 = (const float*)d_in[6];
  const float* W2 = (const float*)d_in[7];
  const float* b2 = (const float*)d_in[8];
  const float* W3 = (const float*)d_in[9];
  const float* b3 = (const float*)d_in[10];
  const float* g0 = (const float*)d_in[11];
  const float* be0 = (const float*)d_in[12];
  const float* g1 = (const float*)d_in[13];
  const float* be1 = (const float*)d_in[14];
  const float* g2 = (const float*)d_in[15];
  const float* be2 = (const float*)d_in[16];
  const float* wl = (const float*)d_in[17];
  const float* bl = (const float*)d_in[18];
  float* out = (float*)d_out;

  const int E = in_sizes[1] / 2;       // 3200000
  const int NB = (NN + 255) / 256;     // 391
  const int BCAP = E / NPART + 65536;  // per-partition capacity
  const int W = (E + PW_C - 1) / PW_C; // waves for binning
  const int GB = (W + 3) / 4;          // blocks (4 waves each)

  char* p = (char*)d_ws;
  int* cnt = (int*)carve(p, (size_t)NN * 4);
  int* row_ptr = (int*)carve(p, (size_t)(NN + 1) * 4);
  int* bsum = (int*)carve(p, 2048);
  int* boff = (int*)carve(p, 2048);
  int* bcur = (int*)carve(p, 256);
  int* bt = (int*)carve(p, 256);
  int* bbase = (int*)carve(p, 256);
  int* pcnt = (int*)carve(p, (size_t)W * NBKT * 4);
  int* pbase = (int*)carve(p, (size_t)W * NBKT * 4);
  int* colv = (int*)carve(p, (size_t)E * 4);
  unsigned long long* bkt = (unsigned long long*)carve(p, (size_t)NPART * BCAP * 8);
  int* dhist = (int*)carve(p, (size_t)NPART * DB * NPB * 4);
  float* invd = (float*)carve(p, (size_t)NN * 4);
  float* s1v = (float*)carve(p, (size_t)NN * 4);
  float* s2v = (float*)carve(p, (size_t)NN * 4);
  _Float16* Wt0 = (_Float16*)carve(p, (size_t)96 * 832 * 2);
  _Float16* Wt1 = (_Float16*)carve(p, (size_t)64 * 1248 * 2);
  _Float16* Wt2 = (_Float16*)carve(p, (size_t)32 * 832 * 2);
  _Float16* Wt3 = (_Float16*)carve(p, (size_t)32 * 416 * 2);
  float* cs = (float*)carve(p, 192 * 4);
  float* csum = cs;
  float* csq = cs + 96;
  float* pacc = (float*)carve(p, (NGRAPH * 20 + NGRAPH) * 4);
  float* zsum = pacc;
  float* gcnt = pacc + NGRAPH * 20;
  _Float16* x16 = (_Float16*)carve(p, (size_t)NN * 64 * 2);
  _Float16* hA16 = (_Float16*)carve(p, (size_t)NN * 96 * 2);
  _Float16* hB16 = (_Float16*)carve(p, (size_t)NN * 96 * 2);
  float* h3 = (float*)x16;  // reuse: x16 dead after L0

  // CSR: 32-bucket (dst,src-quartile) binning -> src-sorted colv rows
  hipMemsetAsync(pacc, 0, (NGRAPH * 20 + NGRAPH) * 4, stream);
  k_pcnt<<<GB, 256, 0, stream>>>(ei, pcnt, E, W);
  k_pscan<<<NBKT, 256, 0, stream>>>(pcnt, pbase, bt, W);
  k_sbase<<<1, 64, 0, stream>>>(bt, bbase, bcur, BCAP);
  k_pbin<<<GB, 256, 0, stream>>>(ei, pbase, bbase, bkt, E, W);
  k_dhist<<<NPART * DB, 256, 0, stream>>>(bkt, bcur, BCAP, dhist);
  k_mergesum<<<NB, 256, 0, stream>>>(dhist, cnt, bsum, NN);
  k_scanb<<<1, 512, 0, stream>>>(bsum, boff, NB);
  k_scatter<<<NB, 256, 0, stream>>>(cnt, boff, row_ptr, NN, E);
  k_nodesc<<<NB, 256, 0, stream>>>(cnt, invd, s1v, s2v, NN);
  k_binfill<<<NPART * DB, 256, 0, stream>>>(bkt, bcur, BCAP, dhist, row_ptr, colv);

  // fp16 swizzled weights + fp16 x
  k_wtprep<<<(96 * 832 + 255) / 256, 256, 0, stream>>>(W0, Wt0, 832, 96, 96);
  k_wtprep<<<(64 * 1248 + 255) / 256, 256, 0, stream>>>(W1, Wt1, 1248, 64, 64);
  k_wtprep<<<(32 * 832 + 255) / 256, 256, 0, stream>>>(W2, Wt2, 832, 32, 32);
  k_wtprep<<<(32 * 416 + 255) / 256, 256, 0, stream>>>(W3, Wt3, 416, 20, 32);
  k_xconv<<<(NN * 64 + 255) / 256, 256, 0, stream>>>(x, x16, NN * 64);

  const int GP = NN / 32;  // 3125

  // Layer 0: (64 -> 96), BN + ReLU (stats fused)
  hipMemsetAsync(cs, 0, 192 * 4, stream);
  k_fused<64, 96, 96, false, true, _Float16><<<GP, 256, 0, stream>>>(
      x16, row_ptr, colv, invd, s1v, s2v, Wt0, b0, hA16, csum, csq);
  k_bn16<<<(NN * 96 / 8 + 255) / 256, 256, 0, stream>>>(hA16, csum, csq, g0, be0, NN, 96, 1);

  // Layer 1: (96 -> 64), BN + ReLU
  hipMemsetAsync(cs, 0, 192 * 4, stream);
  k_fused<96, 64, 64, false, true, _Float16><<<GP, 256, 0, stream>>>(
      hA16, row_ptr, colv, invd, s1v, s2v, Wt1, b1, hB16, csum, csq);
  k_bn16<<<(NN * 64 / 8 + 255) / 256, 256, 0, stream>>>(hB16, csum, csq, g1, be1, NN, 64, 1);

  // Layer 2: (64 -> 32), ReLU fused, no BN
  k_fused<64, 32, 32, true, false, _Float16><<<GP, 256, 0, stream>>>(
      hB16, row_ptr, colv, invd, s1v, s2v, Wt2, b2, hA16, csum, csq);

  // Layer 3: (32 -> 20), BN (no ReLU), fp32 out
  hipMemsetAsync(cs, 0, 192 * 4, stream);
  k_fused<32, 20, 32, false, true, float><<<GP, 256, 0, stream>>>(
      hA16, row_ptr, colv, invd, s1v, s2v, Wt3, b3, h3, csum, csq);
  k_bnf<<<(NN * 20 + 255) / 256, 256, 0, stream>>>(h3, csum, csq, g2, be2, NN, 20, 0);

  // global mean pool + linear + softmax
  k_pool<<<NB, 256, 0, stream>>>(h3, batch, zsum, gcnt, NN);
  k_head<<<1, 64, 0, stream>>>(zsum, gcnt, wl, bl, out);
}